// Round 7
// baseline (28.166 us; speedup 1.0000x reference)
//
#include <hip/hip_runtime.h>
#include <math.h>

// Problem constants (from setup_inputs): xcorr [32, 3, 64, 4096] fp32, nlag = 2048.
#define NB 32
#define NC 3
#define NX 64
#define NT 4096
#define CH_STRIDE ((size_t)NX * NT)

struct Quad { float4 a, b, c, d; };

__device__ __forceinline__ Quad load_row(const float* __restrict__ xr, int wid, int lane) {
    const float* base = xr + (size_t)(wid << 10) + (size_t)(lane << 2);
    Quad q;
    q.a = *reinterpret_cast<const float4*>(base);
    q.b = *reinterpret_cast<const float4*>(base + 256);
    q.c = *reinterpret_cast<const float4*>(base + 512);
    q.d = *reinterpret_cast<const float4*>(base + 768);
    return q;
}

// Branch-free top-2 over 4 consecutive elements. v1 is value-only (its index is
// never needed by the weight formula). Strict > keeps the lowest index on ties,
// matching lax.top_k; equal-to-max duplicates land in v1 via fmax (s1 == s0).
__device__ __forceinline__ void proc4(float a0, float a1, float a2, float a3,
                                      float cl, float cr, int t4,
                                      float& v0, int& i0, float& v1)
{
    // keep = (x == 3-tap max); candidate = x*keep (zeros stay candidates, like ref)
    const float c0 = (a0 >= cl && a0 >= a1) ? a0 : 0.0f;
    const float c1 = (a1 >= a0 && a1 >= a2) ? a1 : 0.0f;
    const float c2 = (a2 >= a1 && a2 >= a3) ? a2 : 0.0f;
    const float c3 = (a3 >= a2 && a3 >= cr) ? a3 : 0.0f;
    bool g;
    g = c0 > v0; v1 = g ? v0 : fmaxf(v1, c0); v0 = fmaxf(v0, c0); i0 = g ? t4     : i0;
    g = c1 > v0; v1 = g ? v0 : fmaxf(v1, c1); v0 = fmaxf(v0, c1); i0 = g ? t4 + 1 : i0;
    g = c2 > v0; v1 = g ? v0 : fmaxf(v1, c2); v0 = fmaxf(v0, c2); i0 = g ? t4 + 2 : i0;
    g = c3 > v0; v1 = g ? v0 : fmaxf(v1, c3); v0 = fmaxf(v0, c3); i0 = g ? t4 + 3 : i0;
}

// Scan one 4096-lag row held in q (wave-contiguous mapping: this wave covers
// [wid*1024, wid*1024+1024), lane covers 4 consecutive elems per group).
// Edge values lmf/rmf (|x| at wid*1024-1 and wid*1024+1024, preloaded) are
// used only for wid>0 / wid<3 respectively.
// Returns wave-merged (v0 value, i0 index, v1 value) identical in all lanes.
__device__ __forceinline__ void scan_row(Quad q, float lmf, float rmf,
                                         int wid, int lane,
                                         float& v0, int& i0, float& v1)
{
    const int base = (wid << 10) + (lane << 2);
    v0 = -1.0f; v1 = -1.0f; i0 = 0;

    const float a00 = fabsf(q.a.x), a01 = fabsf(q.a.y), a02 = fabsf(q.a.z), a03 = fabsf(q.a.w);
    const float a10 = fabsf(q.b.x), a11 = fabsf(q.b.y), a12 = fabsf(q.b.z), a13 = fabsf(q.b.w);
    const float a20 = fabsf(q.c.x), a21 = fabsf(q.c.y), a22 = fabsf(q.c.z), a23 = fabsf(q.c.w);
    const float a30 = fabsf(q.d.x), a31 = fabsf(q.d.y), a32 = fabsf(q.d.z), a33 = fabsf(q.d.w);

    float lm, rm, t;

    // group 0
    lm = __shfl_up(a03, 1);
    lm = (lane == 0) ? ((wid > 0) ? lmf : -INFINITY) : lm;
    rm = __shfl_down(a00, 1);
    t  = __shfl(a10, 0);
    rm = (lane == 63) ? t : rm;
    proc4(a00, a01, a02, a03, lm, rm, base, v0, i0, v1);

    // group 1
    lm = __shfl_up(a13, 1);
    t  = __shfl(a03, 63);
    lm = (lane == 0) ? t : lm;
    rm = __shfl_down(a10, 1);
    t  = __shfl(a20, 0);
    rm = (lane == 63) ? t : rm;
    proc4(a10, a11, a12, a13, lm, rm, base + 256, v0, i0, v1);

    // group 2
    lm = __shfl_up(a23, 1);
    t  = __shfl(a13, 63);
    lm = (lane == 0) ? t : lm;
    rm = __shfl_down(a20, 1);
    t  = __shfl(a30, 0);
    rm = (lane == 63) ? t : rm;
    proc4(a20, a21, a22, a23, lm, rm, base + 512, v0, i0, v1);

    // group 3
    lm = __shfl_up(a33, 1);
    t  = __shfl(a23, 63);
    lm = (lane == 0) ? t : lm;
    rm = __shfl_down(a30, 1);
    rm = (lane == 63) ? ((wid < 3) ? rmf : -INFINITY) : rm;
    proc4(a30, a31, a32, a33, lm, rm, base + 768, v0, i0, v1);

    // wave butterfly top-2 merge (lexicographic on (value desc, index asc))
    #pragma unroll
    for (int off = 1; off < 64; off <<= 1) {
        const float ov0 = __shfl_xor(v0, off);
        const int   oi0 = __shfl_xor(i0, off);
        const float ov1 = __shfl_xor(v1, off);
        const bool big = (ov0 > v0) || (ov0 == v0 && oi0 < i0);
        const float loser = big ? v0 : ov0;
        v1 = fmaxf(fmaxf(v1, ov1), loser);
        v0 = big ? ov0 : v0;
        i0 = big ? oi0 : i0;
    }
}

// Merge the 4 per-wave results of one channel (LDS slots, uniform reads).
__device__ __forceinline__ void merge4(const float sv0c[4], const int si0c[4],
                                       const float sv1c[4],
                                       float& m0, int& mi, float& m1)
{
    m0 = sv0c[0]; mi = si0c[0]; m1 = sv1c[0];
    #pragma unroll
    for (int w = 1; w < 4; ++w) {
        const float b0 = sv0c[w]; const int bi = si0c[w]; const float b1 = sv1c[w];
        const bool big = (b0 > m0) || (b0 == m0 && bi < mi);
        const float loser = big ? m0 : b0;
        m1 = fmaxf(fmaxf(m1, b1), loser);
        m0 = big ? b0 : m0;
        mi = big ? bi : mi;
    }
}

// Uniform per-tile epilogue (verbatim R6 math). All threads merge redundantly;
// tid 0 computes the closed-form grid argmax and stores the 4 outputs.
__device__ __forceinline__ void tile_epilogue(
    const float sv0s[NC][4], const int si0s[NC][4], const float sv1s[NC][4],
    const float* __restrict__ xr0, const float* __restrict__ xr1,
    const float* __restrict__ xr2,
    const int* __restrict__ nlag_p, float* __restrict__ out,
    int g, int tid)
{
    float m00, m01, m02, m10, m11, m12; int p0, p1, p2;
    merge4(sv0s[0], si0s[0], sv1s[0], m00, p0, m10);
    merge4(sv0s[1], si0s[1], sv1s[1], m01, p1, m11);
    merge4(sv0s[2], si0s[2], sv1s[2], m02, p2, m12);

    const float w0 = (0.1f + 3.0f * (m00 - m10)) * (m00 * m00);
    const float w1 = (0.1f + 3.0f * (m01 - m11)) * (m01 * m01);
    const float w2 = (0.1f + 3.0f * (m02 - m12)) * (m02 * m02);

    // channel argmax, first occurrence (ascending c, strict >) — branch-free
    const bool t1 = w1 > w0;
    float bw = t1 ? w1 : w0;
    float bs = t1 ? m01 : m00;
    int   bp = t1 ? p1 : p0;
    const float* xrs = t1 ? xr1 : xr0;
    const bool t2 = w2 > bw;
    bw  = t2 ? w2 : bw;
    bs  = t2 ? m02 : bs;
    bp  = t2 ? p2 : bp;
    xrs = t2 ? xr2 : xrs;

    if (tid == 0) {
        // parabola through clipped neighbors of the selected peak
        const float ym1 = fabsf(xrs[bp > 0 ? bp - 1 : 0]);
        const float yp1 = fabsf(xrs[bp < NT - 1 ? bp + 1 : NT - 1]);
        const float A = 0.5f * (ym1 + yp1) - bs;   // <= 0 up to FP rounding
        const float B = 0.5f * (yp1 - ym1);
        const float C = bs;

        // closed-form grid argmax of yg=(A*xg+B)*xg+C over xg=linspace(-1,1,201):
        // evaluate the 4 grid points bracketing the vertex with the SAME FP
        // formula as the reference; first-max tie-break (ascending candidates).
        int gi; float bv;
        if (A == 0.0f) {
            gi = (B > 0.0f) ? 200 : 0;
            const float xg = 0.01f * (float)(gi - 100);
            bv = (A * xg + B) * xg + C;
        } else {
            float gv = (1.0f - 0.5f * B / A) * 100.0f;  // vertex in grid coords
            gv = fminf(fmaxf(gv, 0.0f), 200.0f);
            const int glo = (int)gv;
            bv = -INFINITY; gi = 0;
            #pragma unroll
            for (int d = -1; d <= 2; ++d) {
                int gg = glo + d;
                gg = gg < 0 ? 0 : (gg > 200 ? 200 : gg);
                const float xg = 0.01f * (float)(gg - 100);
                const float yg = (A * xg + B) * xg + C;
                if (yg > bv) { bv = yg; gi = gg; }      // strict > = first occurrence
            }
        }

        const float fidx = (float)bp + 0.01f * (float)(gi - 100);
        const float nlagf = (float)(*nlag_p);
        const float shift_idx = fidx - nlagf;
        const int n = NB * NX;
        out[0 * n + g] = bv;                  // max_cc (interpolated score)
        out[1 * n + g] = bw;                  // weight
        out[2 * n + g] = shift_idx / 100.0f;  // shift_t (SAMPLING_RATE = 100)
        out[3 * n + g] = shift_idx;           // shift_idx
    }
}

// Persistent 2-tile pipelined kernel: grid = 1024 blocks, block handles tiles
// gA=2*bid, gB=2*bid+1 (adjacent (b,x) pairs -> adjacent 16 KB rows). Tile B's
// loads are issued during tile A's compute so memory stays busy through A's
// scans AND its reduction tail. LDS result slots are double-buffered per tile.
__global__ __launch_bounds__(256) void detect_peaks_kernel(
    const float* __restrict__ xcorr,
    const int*   __restrict__ nlag_p,
    float* __restrict__ out)
{
    __shared__ float sv0[2][NC][4], sv1[2][NC][4];
    __shared__ int   si0[2][NC][4];

    const int bid  = blockIdx.x;            // 0..1023
    const int tid  = threadIdx.x;
    const int lane = tid & 63;
    const int wid  = tid >> 6;

    const int gA = 2 * bid;                 // tile index == b*NX + x
    const int gB = 2 * bid + 1;

    const float* __restrict__ xA0 = xcorr + ((size_t)((gA >> 6) * NC) * NX + (gA & 63)) * NT;
    const float* __restrict__ xA1 = xA0 + CH_STRIDE;
    const float* __restrict__ xA2 = xA0 + 2 * CH_STRIDE;
    const float* __restrict__ xB0 = xcorr + ((size_t)((gB >> 6) * NC) * NX + (gB & 63)) * NT;
    const float* __restrict__ xB1 = xB0 + CH_STRIDE;
    const float* __restrict__ xB2 = xB0 + 2 * CH_STRIDE;

    const int liE = (wid > 0) ? (wid << 10) - 1    : 0;
    const int riE = (wid < 3) ? (wid << 10) + 1024 : NT - 1;

    // ---- load burst: all of tile A, plus tile B's edges + row 0 ----
    Quad qA0 = load_row(xA0, wid, lane);
    Quad qA1 = load_row(xA1, wid, lane);
    Quad qA2 = load_row(xA2, wid, lane);
    const float lA0 = xA0[liE], rA0 = xA0[riE];
    const float lA1 = xA1[liE], rA1 = xA1[riE];
    const float lA2 = xA2[liE], rA2 = xA2[riE];
    Quad qB0 = load_row(xB0, wid, lane);
    const float lB0 = xB0[liE], rB0 = xB0[riE];
    const float lB1 = xB1[liE], rB1 = xB1[riE];
    const float lB2 = xB2[liE], rB2 = xB2[riE];

    float v0, v1; int i0;

    // ---- tile A scans, interleaved with tile B row loads ----
    scan_row(qA0, fabsf(lA0), fabsf(rA0), wid, lane, v0, i0, v1);
    Quad qB1 = load_row(xB1, wid, lane);
    if (lane == 0) { sv0[0][0][wid] = v0; si0[0][0][wid] = i0; sv1[0][0][wid] = v1; }

    scan_row(qA1, fabsf(lA1), fabsf(rA1), wid, lane, v0, i0, v1);
    Quad qB2 = load_row(xB2, wid, lane);
    if (lane == 0) { sv0[0][1][wid] = v0; si0[0][1][wid] = i0; sv1[0][1][wid] = v1; }

    scan_row(qA2, fabsf(lA2), fabsf(rA2), wid, lane, v0, i0, v1);
    if (lane == 0) { sv0[0][2][wid] = v0; si0[0][2][wid] = i0; sv1[0][2][wid] = v1; }

    __syncthreads();                        // slot 0 complete

    // tile A tail runs while tile B's 12 row loads are still in flight
    tile_epilogue(sv0[0], si0[0], sv1[0], xA0, xA1, xA2, nlag_p, out, gA, tid);

    // ---- tile B scans ----
    scan_row(qB0, fabsf(lB0), fabsf(rB0), wid, lane, v0, i0, v1);
    if (lane == 0) { sv0[1][0][wid] = v0; si0[1][0][wid] = i0; sv1[1][0][wid] = v1; }

    scan_row(qB1, fabsf(lB1), fabsf(rB1), wid, lane, v0, i0, v1);
    if (lane == 0) { sv0[1][1][wid] = v0; si0[1][1][wid] = i0; sv1[1][1][wid] = v1; }

    scan_row(qB2, fabsf(lB2), fabsf(rB2), wid, lane, v0, i0, v1);
    if (lane == 0) { sv0[1][2][wid] = v0; si0[1][2][wid] = i0; sv1[1][2][wid] = v1; }

    __syncthreads();                        // slot 1 complete

    tile_epilogue(sv0[1], si0[1], sv1[1], xB0, xB1, xB2, nlag_p, out, gB, tid);
}

extern "C" void kernel_launch(void* const* d_in, const int* in_sizes, int n_in,
                              void* d_out, int out_size, void* d_ws, size_t ws_size,
                              hipStream_t stream) {
    const float* xcorr  = (const float*)d_in[0];
    const int*   nlag_p = (const int*)d_in[1];
    float* out = (float*)d_out;

    detect_peaks_kernel<<<(NB * NX) / 2, 256, 0, stream>>>(xcorr, nlag_p, out);
}

// Round 8
// 24.695 us; speedup vs baseline: 1.1406x; 1.1406x over previous
//
#include <hip/hip_runtime.h>
#include <math.h>

// Problem constants (from setup_inputs): xcorr [32, 3, 64, 4096] fp32, nlag = 2048.
#define NB 32
#define NC 3
#define NX 64
#define NT 4096
#define NROWS (NB * NC * NX)   // 6144

struct Quad { float4 a, b, c, d; };

__device__ __forceinline__ Quad load_row(const float* __restrict__ xr, int wid, int lane) {
    const float* base = xr + (size_t)(wid << 10) + (size_t)(lane << 2);
    Quad q;
    q.a = *reinterpret_cast<const float4*>(base);
    q.b = *reinterpret_cast<const float4*>(base + 256);
    q.c = *reinterpret_cast<const float4*>(base + 512);
    q.d = *reinterpret_cast<const float4*>(base + 768);
    return q;
}

// Branch-free top-2 over 4 consecutive elements. v1 is value-only (its index is
// never needed by the weight formula). Strict > keeps the lowest index on ties,
// matching lax.top_k; equal-to-max duplicates land in v1 via fmax (s1 == s0).
__device__ __forceinline__ void proc4(float a0, float a1, float a2, float a3,
                                      float cl, float cr, int t4,
                                      float& v0, int& i0, float& v1)
{
    // keep = (x == 3-tap max); candidate = x*keep (zeros stay candidates, like ref)
    const float c0 = (a0 >= cl && a0 >= a1) ? a0 : 0.0f;
    const float c1 = (a1 >= a0 && a1 >= a2) ? a1 : 0.0f;
    const float c2 = (a2 >= a1 && a2 >= a3) ? a2 : 0.0f;
    const float c3 = (a3 >= a2 && a3 >= cr) ? a3 : 0.0f;
    bool g;
    g = c0 > v0; v1 = g ? v0 : fmaxf(v1, c0); v0 = fmaxf(v0, c0); i0 = g ? t4     : i0;
    g = c1 > v0; v1 = g ? v0 : fmaxf(v1, c1); v0 = fmaxf(v0, c1); i0 = g ? t4 + 1 : i0;
    g = c2 > v0; v1 = g ? v0 : fmaxf(v1, c2); v0 = fmaxf(v0, c2); i0 = g ? t4 + 2 : i0;
    g = c3 > v0; v1 = g ? v0 : fmaxf(v1, c3); v0 = fmaxf(v0, c3); i0 = g ? t4 + 3 : i0;
}

// Scan one 4096-lag row held in q (wave-contiguous mapping: this wave covers
// [wid*1024, wid*1024+1024), lane covers 4 consecutive elems per group).
// Edge values lmf/rmf (|x| at wid*1024-1 and wid*1024+1024, preloaded) are
// used only for wid>0 / wid<3 respectively.
// Returns wave-merged (v0 value, i0 index, v1 value) identical in all lanes.
__device__ __forceinline__ void scan_row(Quad q, float lmf, float rmf,
                                         int wid, int lane,
                                         float& v0, int& i0, float& v1)
{
    const int base = (wid << 10) + (lane << 2);
    v0 = -1.0f; v1 = -1.0f; i0 = 0;

    const float a00 = fabsf(q.a.x), a01 = fabsf(q.a.y), a02 = fabsf(q.a.z), a03 = fabsf(q.a.w);
    const float a10 = fabsf(q.b.x), a11 = fabsf(q.b.y), a12 = fabsf(q.b.z), a13 = fabsf(q.b.w);
    const float a20 = fabsf(q.c.x), a21 = fabsf(q.c.y), a22 = fabsf(q.c.z), a23 = fabsf(q.c.w);
    const float a30 = fabsf(q.d.x), a31 = fabsf(q.d.y), a32 = fabsf(q.d.z), a33 = fabsf(q.d.w);

    float lm, rm, t;

    // group 0
    lm = __shfl_up(a03, 1);
    lm = (lane == 0) ? ((wid > 0) ? lmf : -INFINITY) : lm;
    rm = __shfl_down(a00, 1);
    t  = __shfl(a10, 0);
    rm = (lane == 63) ? t : rm;
    proc4(a00, a01, a02, a03, lm, rm, base, v0, i0, v1);

    // group 1
    lm = __shfl_up(a13, 1);
    t  = __shfl(a03, 63);
    lm = (lane == 0) ? t : lm;
    rm = __shfl_down(a10, 1);
    t  = __shfl(a20, 0);
    rm = (lane == 63) ? t : rm;
    proc4(a10, a11, a12, a13, lm, rm, base + 256, v0, i0, v1);

    // group 2
    lm = __shfl_up(a23, 1);
    t  = __shfl(a13, 63);
    lm = (lane == 0) ? t : lm;
    rm = __shfl_down(a20, 1);
    t  = __shfl(a30, 0);
    rm = (lane == 63) ? t : rm;
    proc4(a20, a21, a22, a23, lm, rm, base + 512, v0, i0, v1);

    // group 3
    lm = __shfl_up(a33, 1);
    t  = __shfl(a23, 63);
    lm = (lane == 0) ? t : lm;
    rm = __shfl_down(a30, 1);
    rm = (lane == 63) ? ((wid < 3) ? rmf : -INFINITY) : rm;
    proc4(a30, a31, a32, a33, lm, rm, base + 768, v0, i0, v1);

    // wave butterfly top-2 merge (lexicographic on (value desc, index asc))
    #pragma unroll
    for (int off = 1; off < 64; off <<= 1) {
        const float ov0 = __shfl_xor(v0, off);
        const int   oi0 = __shfl_xor(i0, off);
        const float ov1 = __shfl_xor(v1, off);
        const bool big = (ov0 > v0) || (ov0 == v0 && oi0 < i0);
        const float loser = big ? v0 : ov0;
        v1 = fmaxf(fmaxf(v1, ov1), loser);
        v0 = big ? ov0 : v0;
        i0 = big ? oi0 : i0;
    }
}

// Merge the 4 per-wave results of one row (LDS slots, uniform reads).
__device__ __forceinline__ void merge4(const float sv0c[4], const int si0c[4],
                                       const float sv1c[4],
                                       float& m0, int& mi, float& m1)
{
    m0 = sv0c[0]; mi = si0c[0]; m1 = sv1c[0];
    #pragma unroll
    for (int w = 1; w < 4; ++w) {
        const float b0 = sv0c[w]; const int bi = si0c[w]; const float b1 = sv1c[w];
        const bool big = (b0 > m0) || (b0 == m0 && bi < mi);
        const float loser = big ? m0 : b0;
        m1 = fmaxf(fmaxf(m1, b1), loser);
        m0 = big ? b0 : m0;
        mi = big ? bi : mi;
    }
}

// Phase 1: one lean block per row (6144 blocks). One Quad per wave, R6's scan,
// LDS merge, write the row's (v0, i0, v1) triple to workspace.
__global__ __launch_bounds__(256) void scan_rows_kernel(
    const float* __restrict__ xcorr,
    float* __restrict__ wsv0, int* __restrict__ wsi0, float* __restrict__ wsv1)
{
    __shared__ float sv0[4], sv1[4];
    __shared__ int   si0[4];

    const int row  = blockIdx.x;           // 0..NROWS-1
    const int tid  = threadIdx.x;
    const int lane = tid & 63;
    const int wid  = tid >> 6;

    const float* __restrict__ xr = xcorr + (size_t)row * NT;

    Quad q = load_row(xr, wid, lane);
    const int liE = (wid > 0) ? (wid << 10) - 1    : 0;
    const int riE = (wid < 3) ? (wid << 10) + 1024 : NT - 1;
    const float lm = fabsf(xr[liE]);
    const float rm = fabsf(xr[riE]);

    float v0, v1; int i0;
    scan_row(q, lm, rm, wid, lane, v0, i0, v1);

    if (lane == 0) { sv0[wid] = v0; si0[wid] = i0; sv1[wid] = v1; }
    __syncthreads();

    if (tid == 0) {
        float m0, m1; int mi;
        merge4(sv0, si0, sv1, m0, mi, m1);
        wsv0[row] = m0;
        wsi0[row] = mi;
        wsv1[row] = m1;
    }
}

// Phase 2: one thread per (b,x) tile. Merge the 3 channel triples, pick the
// max-weight channel (first occurrence), closed-form grid argmax epilogue
// (verbatim R6 math), write the 4 stacked outputs.
__global__ __launch_bounds__(256) void epilogue_kernel(
    const float* __restrict__ xcorr,
    const float* __restrict__ wsv0, const int* __restrict__ wsi0,
    const float* __restrict__ wsv1,
    const int*   __restrict__ nlag_p,
    float* __restrict__ out)
{
    const int g = blockIdx.x * 256 + threadIdx.x;   // tile index = b*NX + x
    if (g >= NB * NX) return;
    const int b = g >> 6;
    const int x = g & 63;

    const int r0 = (b * NC + 0) * NX + x;
    const int r1 = (b * NC + 1) * NX + x;
    const int r2 = (b * NC + 2) * NX + x;

    const float m00 = wsv0[r0], m10 = wsv1[r0]; const int p0 = wsi0[r0];
    const float m01 = wsv0[r1], m11 = wsv1[r1]; const int p1 = wsi0[r1];
    const float m02 = wsv0[r2], m12 = wsv1[r2]; const int p2 = wsi0[r2];

    const float w0 = (0.1f + 3.0f * (m00 - m10)) * (m00 * m00);
    const float w1 = (0.1f + 3.0f * (m01 - m11)) * (m01 * m01);
    const float w2 = (0.1f + 3.0f * (m02 - m12)) * (m02 * m02);

    // channel argmax, first occurrence (ascending c, strict >) — branch-free
    const bool t1 = w1 > w0;
    float bw = t1 ? w1 : w0;
    float bs = t1 ? m01 : m00;
    int   bp = t1 ? p1 : p0;
    int   rs = t1 ? r1 : r0;
    const bool t2 = w2 > bw;
    bw = t2 ? w2 : bw;
    bs = t2 ? m02 : bs;
    bp = t2 ? p2 : bp;
    rs = t2 ? r2 : rs;

    const float* __restrict__ xrs = xcorr + (size_t)rs * NT;

    // parabola through clipped neighbors of the selected peak
    const float ym1 = fabsf(xrs[bp > 0 ? bp - 1 : 0]);
    const float yp1 = fabsf(xrs[bp < NT - 1 ? bp + 1 : NT - 1]);
    const float A = 0.5f * (ym1 + yp1) - bs;   // <= 0 up to FP rounding
    const float B = 0.5f * (yp1 - ym1);
    const float C = bs;

    // closed-form grid argmax of yg=(A*xg+B)*xg+C over xg=linspace(-1,1,201):
    // evaluate the 4 grid points bracketing the vertex with the SAME FP
    // formula as the reference; first-max tie-break (ascending candidates).
    int gi; float bv;
    if (A == 0.0f) {
        gi = (B > 0.0f) ? 200 : 0;
        const float xg = 0.01f * (float)(gi - 100);
        bv = (A * xg + B) * xg + C;
    } else {
        float gv = (1.0f - 0.5f * B / A) * 100.0f;  // vertex in grid coords
        gv = fminf(fmaxf(gv, 0.0f), 200.0f);
        const int glo = (int)gv;
        bv = -INFINITY; gi = 0;
        #pragma unroll
        for (int d = -1; d <= 2; ++d) {
            int gg = glo + d;
            gg = gg < 0 ? 0 : (gg > 200 ? 200 : gg);
            const float xg = 0.01f * (float)(gg - 100);
            const float yg = (A * xg + B) * xg + C;
            if (yg > bv) { bv = yg; gi = gg; }          // strict > = first occurrence
        }
    }

    const float fidx = (float)bp + 0.01f * (float)(gi - 100);
    const float nlagf = (float)(*nlag_p);
    const float shift_idx = fidx - nlagf;
    const int n = NB * NX;
    out[0 * n + g] = bv;                  // max_cc (interpolated score)
    out[1 * n + g] = bw;                  // weight
    out[2 * n + g] = shift_idx / 100.0f;  // shift_t (SAMPLING_RATE = 100)
    out[3 * n + g] = shift_idx;           // shift_idx
}

extern "C" void kernel_launch(void* const* d_in, const int* in_sizes, int n_in,
                              void* d_out, int out_size, void* d_ws, size_t ws_size,
                              hipStream_t stream) {
    const float* xcorr  = (const float*)d_in[0];
    const int*   nlag_p = (const int*)d_in[1];
    float* out = (float*)d_out;

    float* ws   = (float*)d_ws;
    float* wsv0 = ws;                       // [NROWS]
    int*   wsi0 = (int*)(ws + NROWS);       // [NROWS]
    float* wsv1 = ws + 2 * NROWS;           // [NROWS]

    scan_rows_kernel<<<NROWS, 256, 0, stream>>>(xcorr, wsv0, wsi0, wsv1);

    epilogue_kernel<<<(NB * NX + 255) / 256, 256, 0, stream>>>(
        xcorr, wsv0, wsi0, wsv1, nlag_p, out);
}